// Round 3
// baseline (238.472 us; speedup 1.0000x reference)
//
#include <hip/hip_runtime.h>
#include <hip/hip_fp16.h>

// Problem constants (from reference)
constexpr int B        = 2;
constexpr int N_IN     = 262144;
constexpr int D        = 32;
constexpr int N_OUT    = 65536;
constexpr int K        = 4;
constexpr int NK       = 9;
constexpr int P        = B * N_OUT * K;        // 524288 output points
constexpr int PPB      = N_OUT * K;            // 262144 points per batch
constexpr size_t XTOT  = (size_t)B * N_IN * D; // 16,777,216 feature elements

typedef _Float16 half4v __attribute__((ext_vector_type(4)));
typedef _Float16 half8v __attribute__((ext_vector_type(8)));

// ---------------- pre-pass 1: fp32 feature table -> fp16 table in d_ws ------
__global__ __launch_bounds__(256) void cvt_fp16_kernel(
    const float* __restrict__ x, _Float16* __restrict__ xh)
{
    const size_t i = (size_t)(blockIdx.x * 256 + threadIdx.x) * 8;
    const float4 a = *reinterpret_cast<const float4*>(x + i);
    const float4 b = *reinterpret_cast<const float4*>(x + i + 4);
    half8v h;
    h[0] = (_Float16)a.x; h[1] = (_Float16)a.y;
    h[2] = (_Float16)a.z; h[3] = (_Float16)a.w;
    h[4] = (_Float16)b.x; h[5] = (_Float16)b.y;
    h[6] = (_Float16)b.z; h[7] = (_Float16)b.w;
    *reinterpret_cast<half8v*>(xh + i) = h;
}

// ---------------- pre-pass 2: coords_in (2,B,N_IN) -> interleaved float2 -----
__global__ __launch_bounds__(256) void pack_coords_kernel(
    const float* __restrict__ cin, float2* __restrict__ cp)
{
    const int i = blockIdx.x * 256 + threadIdx.x;   // 0 .. B*N_IN-1
    cp[i] = make_float2(cin[i], cin[B * N_IN + i]);
}

// ---------------- main kernel ------------------------------------------------
// 8 lanes per point, each lane handles 4 channels.
// blockIdx remapped so batch 0 -> XCDs 0-3, batch 1 -> XCDs 4-7 (round-robin
// blockIdx%8 -> XCD heuristic; if mapping differs it's a harmless permutation).
__global__ __launch_bounds__(256) void projection_kernel_h(
    const _Float16* __restrict__ xh,      // (B, N_IN, D) fp16
    const float2*   __restrict__ cpack,   // (B, N_IN) float2
    const float*    __restrict__ coords_out, // (2, P)
    const float*    __restrict__ sigma,   // (D,)
    const int*      __restrict__ nidx,    // (P, NK)
    float*          __restrict__ out)     // (P, D)
{
    const int bid   = blockIdx.x;         // 0..16383
    const int xcd   = bid & 7;
    const int j     = bid >> 3;
    const int batch = xcd >> 2;                       // 0 or 1
    const int bbi   = j * 4 + (xcd & 3);              // 0..8191 within batch
    const int point = batch * PPB + bbi * 32 + (threadIdx.x >> 3);
    const int q     = threadIdx.x & 7;

    const int cbase = batch * N_IN;

    const float cox = coords_out[point];
    const float coy = coords_out[P + point];

    const float4 sg = *reinterpret_cast<const float4*>(sigma + q * 4);
    const float s0 = 1.0f / (2.0f * sg.x * sg.x);
    const float s1 = 1.0f / (2.0f * sg.y * sg.y);
    const float s2 = 1.0f / (2.0f * sg.z * sg.z);
    const float s3 = 1.0f / (2.0f * sg.w * sg.w);
    const bool uni = (sg.x == sg.y) && (sg.y == sg.z) && (sg.z == sg.w);

    // ---- prefetch phase: maximize outstanding gathers ----
    int idxs[NK];
    const int* __restrict__ ip = nidx + (size_t)point * NK;
    #pragma unroll
    for (int t = 0; t < NK; ++t) idxs[t] = ip[t];

    float2 c[NK];
    #pragma unroll
    for (int t = 0; t < NK; ++t) c[t] = cpack[cbase + idxs[t]];

    half4v f[NK];
    #pragma unroll
    for (int t = 0; t < NK; ++t)
        f[t] = *reinterpret_cast<const half4v*>(
            xh + (size_t)(cbase + idxs[t]) * D + q * 4);

    float4 num = make_float4(0.f, 0.f, 0.f, 0.f);
    float4 den = make_float4(0.f, 0.f, 0.f, 0.f);

    if (uni) {
        // all 4 channel sigmas equal -> one exp per neighbor
        #pragma unroll
        for (int t = 0; t < NK; ++t) {
            const float dx = cox - c[t].x;
            const float dy = coy - c[t].y;
            const float d2 = dx * dx + dy * dy;
            const float w  = __expf(-d2 * s0);
            num.x += w * (float)f[t][0];
            num.y += w * (float)f[t][1];
            num.z += w * (float)f[t][2];
            num.w += w * (float)f[t][3];
            den.x += w;
        }
        den.y = den.x; den.z = den.x; den.w = den.x;
    } else {
        #pragma unroll
        for (int t = 0; t < NK; ++t) {
            const float dx = cox - c[t].x;
            const float dy = coy - c[t].y;
            const float d2 = dx * dx + dy * dy;
            const float w0 = __expf(-d2 * s0);
            const float w1 = __expf(-d2 * s1);
            const float w2 = __expf(-d2 * s2);
            const float w3 = __expf(-d2 * s3);
            num.x += w0 * (float)f[t][0];  den.x += w0;
            num.y += w1 * (float)f[t][1];  den.y += w1;
            num.z += w2 * (float)f[t][2];  den.z += w2;
            num.w += w3 * (float)f[t][3];  den.w += w3;
        }
    }

    float4 o;
    o.x = num.x / (den.x + 1e-9f);
    o.y = num.y / (den.y + 1e-9f);
    o.z = num.z / (den.z + 1e-9f);
    o.w = num.w / (den.w + 1e-9f);

    *reinterpret_cast<float4*>(out + (size_t)point * D + q * 4) = o;
}

// ---------------- fallback: proven fp32 path (if ws too small) ---------------
__global__ __launch_bounds__(256) void projection_kernel_f32(
    const float* __restrict__ x,
    const float* __restrict__ coords_in,
    const float* __restrict__ coords_out,
    const float* __restrict__ sigma,
    const int*   __restrict__ nidx,
    float*       __restrict__ out)
{
    const int tid   = blockIdx.x * 256 + threadIdx.x;
    const int point = tid >> 3;
    const int q     = tid & 7;
    const int b     = point / PPB;
    const int cbase = b * N_IN;

    const float cox = coords_out[point];
    const float coy = coords_out[P + point];

    const float4 sg = *reinterpret_cast<const float4*>(sigma + q * 4);
    const float s0 = 1.0f / (2.0f * sg.x * sg.x);
    const float s1 = 1.0f / (2.0f * sg.y * sg.y);
    const float s2 = 1.0f / (2.0f * sg.z * sg.z);
    const float s3 = 1.0f / (2.0f * sg.w * sg.w);

    float4 num = make_float4(0.f, 0.f, 0.f, 0.f);
    float4 den = make_float4(0.f, 0.f, 0.f, 0.f);
    const int* __restrict__ ip = nidx + (size_t)point * NK;

    #pragma unroll
    for (int nk = 0; nk < NK; ++nk) {
        const int idx = ip[nk];
        const float cx = coords_in[cbase + idx];
        const float cy = coords_in[B * N_IN + cbase + idx];
        const float dx = cox - cx;
        const float dy = coy - cy;
        const float d2 = dx * dx + dy * dy;
        const float4 f = *reinterpret_cast<const float4*>(
            x + (size_t)(cbase + idx) * D + q * 4);
        const float w0 = __expf(-d2 * s0);
        const float w1 = __expf(-d2 * s1);
        const float w2 = __expf(-d2 * s2);
        const float w3 = __expf(-d2 * s3);
        num.x += w0 * f.x;  den.x += w0;
        num.y += w1 * f.y;  den.y += w1;
        num.z += w2 * f.z;  den.z += w2;
        num.w += w3 * f.w;  den.w += w3;
    }

    float4 o;
    o.x = num.x / (den.x + 1e-9f);
    o.y = num.y / (den.y + 1e-9f);
    o.z = num.z / (den.z + 1e-9f);
    o.w = num.w / (den.w + 1e-9f);
    *reinterpret_cast<float4*>(out + (size_t)point * D + q * 4) = o;
}

extern "C" void kernel_launch(void* const* d_in, const int* in_sizes, int n_in,
                              void* d_out, int out_size, void* d_ws, size_t ws_size,
                              hipStream_t stream) {
    const float* x      = (const float*)d_in[0];
    const float* cin    = (const float*)d_in[1];
    const float* cout_  = (const float*)d_in[2];
    const float* sigma  = (const float*)d_in[3];
    const int*   nidx   = (const int*)  d_in[4];
    float*       outp   = (float*)d_out;

    const int block = 256;
    const int grid_main = (P * 8) / block;   // 16384

    const size_t xh_bytes = XTOT * sizeof(_Float16);            // 33.55 MB
    const size_t cp_bytes = (size_t)B * N_IN * sizeof(float2);  //  4.19 MB

    if (ws_size >= xh_bytes + cp_bytes) {
        _Float16* xh = (_Float16*)d_ws;
        float2*   cp = (float2*)((char*)d_ws + xh_bytes);
        cvt_fp16_kernel<<<(int)(XTOT / 8 / block), block, 0, stream>>>(x, xh);
        pack_coords_kernel<<<(B * N_IN) / block, block, 0, stream>>>(cin, cp);
        projection_kernel_h<<<grid_main, block, 0, stream>>>(
            xh, cp, cout_, sigma, nidx, outp);
    } else {
        projection_kernel_f32<<<grid_main, block, 0, stream>>>(
            x, cin, cout_, sigma, nidx, outp);
    }
}

// Round 5
// 218.431 us; speedup vs baseline: 1.0918x; 1.0918x over previous
//
#include <hip/hip_runtime.h>
#include <hip/hip_fp16.h>

// Problem constants (from reference)
constexpr int B        = 2;
constexpr int N_IN     = 262144;
constexpr int D        = 32;
constexpr int N_OUT    = 65536;
constexpr int K        = 4;
constexpr int NK       = 9;
constexpr int P        = B * N_OUT * K;        // 524288 output points
constexpr int PPB      = N_OUT * K;            // 262144 points per batch
constexpr size_t XTOT  = (size_t)B * N_IN * D; // 16,777,216 feature elements

typedef _Float16 half2v __attribute__((ext_vector_type(2)));
typedef _Float16 half8v __attribute__((ext_vector_type(8)));
typedef float    f4v    __attribute__((ext_vector_type(4)));

// ---------------- pre-pass 1: fp32 feature table -> fp16 table in d_ws ------
__global__ __launch_bounds__(256) void cvt_fp16_kernel(
    const float* __restrict__ x, _Float16* __restrict__ xh)
{
    const size_t i = (size_t)(blockIdx.x * 256 + threadIdx.x) * 8;
    const float4 a = *reinterpret_cast<const float4*>(x + i);
    const float4 b = *reinterpret_cast<const float4*>(x + i + 4);
    half8v h;
    h[0] = (_Float16)a.x; h[1] = (_Float16)a.y;
    h[2] = (_Float16)a.z; h[3] = (_Float16)a.w;
    h[4] = (_Float16)b.x; h[5] = (_Float16)b.y;
    h[6] = (_Float16)b.z; h[7] = (_Float16)b.w;
    *reinterpret_cast<half8v*>(xh + i) = h;
}

// ---------------- pre-pass 2: coords_in (2,B,N_IN) -> fp16 half2 table ------
// coords in [0,1): fp16 abs err <= 2^-12 -> w rel err ~1e-4. Halves the L2
// footprint of the coord table (1 MB/batch) vs float2.
__global__ __launch_bounds__(256) void pack_coords_kernel(
    const float* __restrict__ cin, half2v* __restrict__ cp)
{
    const int i = blockIdx.x * 256 + threadIdx.x;   // 0 .. B*N_IN-1
    half2v h;
    h[0] = (_Float16)cin[i];
    h[1] = (_Float16)cin[B * N_IN + i];
    cp[i] = h;
}

// ---------------- main kernel ------------------------------------------------
// 4 lanes per point; each lane owns 8 channels via one 16 B half8 load.
// Per wave: 16 points -> each feature-gather instruction requests 16 distinct
// 64 B rows (2x the lines-in-flight of the 8-lane variant, half the waves).
// blockIdx%8 -> XCD round-robin heuristic keeps one batch per XCD half.
__global__ __launch_bounds__(256) void projection_kernel_h(
    const _Float16* __restrict__ xh,         // (B, N_IN, D) fp16
    const half2v*   __restrict__ cpack,      // (B, N_IN) fp16 pairs
    const float*    __restrict__ coords_out, // (2, P)
    const float*    __restrict__ sigma,      // (D,)
    const int*      __restrict__ nidx,       // (P, NK)
    float*          __restrict__ out)        // (P, D)
{
    const int bid   = blockIdx.x;            // 0..8191
    const int xcd   = bid & 7;
    const int j     = bid >> 3;
    const int batch = xcd >> 2;                       // 0 or 1
    const int bbi   = j * 4 + (xcd & 3);              // 0..4095 within batch
    const int point = batch * PPB + bbi * 64 + (threadIdx.x >> 2);
    const int h     = threadIdx.x & 3;                // channel octet: 8h..8h+7

    const int cbase = batch * N_IN;

    const float cox = __builtin_nontemporal_load(coords_out + point);
    const float coy = __builtin_nontemporal_load(coords_out + P + point);

    const float4 sg0 = *reinterpret_cast<const float4*>(sigma + h * 8);
    const float4 sg1 = *reinterpret_cast<const float4*>(sigma + h * 8 + 4);
    float s[8];
    s[0] = 1.0f / (2.0f * sg0.x * sg0.x); s[1] = 1.0f / (2.0f * sg0.y * sg0.y);
    s[2] = 1.0f / (2.0f * sg0.z * sg0.z); s[3] = 1.0f / (2.0f * sg0.w * sg0.w);
    s[4] = 1.0f / (2.0f * sg1.x * sg1.x); s[5] = 1.0f / (2.0f * sg1.y * sg1.y);
    s[6] = 1.0f / (2.0f * sg1.z * sg1.z); s[7] = 1.0f / (2.0f * sg1.w * sg1.w);
    bool uni = true;
    #pragma unroll
    for (int k = 1; k < 8; ++k) uni = uni && (s[k] == s[0]);

    // ---- prefetch: all idx, then all coord gathers, then all feature rows --
    int idxs[NK];
    const int* __restrict__ ip = nidx + (size_t)point * NK;
    #pragma unroll
    for (int t = 0; t < NK; ++t) idxs[t] = __builtin_nontemporal_load(ip + t);

    half2v c[NK];
    #pragma unroll
    for (int t = 0; t < NK; ++t) c[t] = cpack[cbase + idxs[t]];

    half8v f[NK];
    #pragma unroll
    for (int t = 0; t < NK; ++t)
        f[t] = *reinterpret_cast<const half8v*>(
            xh + (size_t)(cbase + idxs[t]) * D + h * 8);

    float num[8];
    #pragma unroll
    for (int k = 0; k < 8; ++k) num[k] = 0.f;

    float den[8];
    #pragma unroll
    for (int k = 0; k < 8; ++k) den[k] = 0.f;

    if (uni) {
        #pragma unroll
        for (int t = 0; t < NK; ++t) {
            const float dx = cox - (float)c[t][0];
            const float dy = coy - (float)c[t][1];
            const float w  = __expf(-(dx * dx + dy * dy) * s[0]);
            den[0] += w;
            #pragma unroll
            for (int k = 0; k < 8; ++k) num[k] += w * (float)f[t][k];
        }
        #pragma unroll
        for (int k = 1; k < 8; ++k) den[k] = den[0];
    } else {
        #pragma unroll
        for (int t = 0; t < NK; ++t) {
            const float dx = cox - (float)c[t][0];
            const float dy = coy - (float)c[t][1];
            const float d2 = dx * dx + dy * dy;
            #pragma unroll
            for (int k = 0; k < 8; ++k) {
                const float w = __expf(-d2 * s[k]);
                num[k] += w * (float)f[t][k];
                den[k] += w;
            }
        }
    }

    float* op = out + (size_t)point * D + h * 8;
    f4v o0, o1;
    o0.x = num[0] / (den[0] + 1e-9f); o0.y = num[1] / (den[1] + 1e-9f);
    o0.z = num[2] / (den[2] + 1e-9f); o0.w = num[3] / (den[3] + 1e-9f);
    o1.x = num[4] / (den[4] + 1e-9f); o1.y = num[5] / (den[5] + 1e-9f);
    o1.z = num[6] / (den[6] + 1e-9f); o1.w = num[7] / (den[7] + 1e-9f);
    // out is never re-read: NT stores keep 65 MB of write-allocate out of L2
    __builtin_nontemporal_store(o0, reinterpret_cast<f4v*>(op));
    __builtin_nontemporal_store(o1, reinterpret_cast<f4v*>(op + 4));
}

// ---------------- fallback: proven fp32 path (if ws too small) ---------------
__global__ __launch_bounds__(256) void projection_kernel_f32(
    const float* __restrict__ x,
    const float* __restrict__ coords_in,
    const float* __restrict__ coords_out,
    const float* __restrict__ sigma,
    const int*   __restrict__ nidx,
    float*       __restrict__ out)
{
    const int tid   = blockIdx.x * 256 + threadIdx.x;
    const int point = tid >> 3;
    const int q     = tid & 7;
    const int b     = point / PPB;
    const int cbase = b * N_IN;

    const float cox = coords_out[point];
    const float coy = coords_out[P + point];

    const float4 sg = *reinterpret_cast<const float4*>(sigma + q * 4);
    const float s0 = 1.0f / (2.0f * sg.x * sg.x);
    const float s1 = 1.0f / (2.0f * sg.y * sg.y);
    const float s2 = 1.0f / (2.0f * sg.z * sg.z);
    const float s3 = 1.0f / (2.0f * sg.w * sg.w);

    float4 num = make_float4(0.f, 0.f, 0.f, 0.f);
    float4 den = make_float4(0.f, 0.f, 0.f, 0.f);
    const int* __restrict__ ip = nidx + (size_t)point * NK;

    #pragma unroll
    for (int nk = 0; nk < NK; ++nk) {
        const int idx = ip[nk];
        const float cx = coords_in[cbase + idx];
        const float cy = coords_in[B * N_IN + cbase + idx];
        const float dx = cox - cx;
        const float dy = coy - cy;
        const float d2 = dx * dx + dy * dy;
        const float4 f = *reinterpret_cast<const float4*>(
            x + (size_t)(cbase + idx) * D + q * 4);
        const float w0 = __expf(-d2 * s0);
        const float w1 = __expf(-d2 * s1);
        const float w2 = __expf(-d2 * s2);
        const float w3 = __expf(-d2 * s3);
        num.x += w0 * f.x;  den.x += w0;
        num.y += w1 * f.y;  den.y += w1;
        num.z += w2 * f.z;  den.z += w2;
        num.w += w3 * f.w;  den.w += w3;
    }

    float4 o;
    o.x = num.x / (den.x + 1e-9f);
    o.y = num.y / (den.y + 1e-9f);
    o.z = num.z / (den.z + 1e-9f);
    o.w = num.w / (den.w + 1e-9f);
    *reinterpret_cast<float4*>(out + (size_t)point * D + q * 4) = o;
}

extern "C" void kernel_launch(void* const* d_in, const int* in_sizes, int n_in,
                              void* d_out, int out_size, void* d_ws, size_t ws_size,
                              hipStream_t stream) {
    const float* x      = (const float*)d_in[0];
    const float* cin    = (const float*)d_in[1];
    const float* cout_  = (const float*)d_in[2];
    const float* sigma  = (const float*)d_in[3];
    const int*   nidx   = (const int*)  d_in[4];
    float*       outp   = (float*)d_out;

    const int block = 256;

    const size_t xh_bytes = XTOT * sizeof(_Float16);            // 33.55 MB
    const size_t cp_bytes = (size_t)B * N_IN * sizeof(half2v);  //  2.10 MB

    if (ws_size >= xh_bytes + cp_bytes) {
        _Float16* xh = (_Float16*)d_ws;
        half2v*   cp = (half2v*)((char*)d_ws + xh_bytes);
        cvt_fp16_kernel<<<(int)(XTOT / 8 / block), block, 0, stream>>>(x, xh);
        pack_coords_kernel<<<(B * N_IN) / block, block, 0, stream>>>(cin, cp);
        const int grid_main = (P * 4) / block;   // 8192
        projection_kernel_h<<<grid_main, block, 0, stream>>>(
            xh, cp, cout_, sigma, nidx, outp);
    } else {
        const int grid_main = (P * 8) / block;   // 16384
        projection_kernel_f32<<<grid_main, block, 0, stream>>>(
            x, cin, cout_, sigma, nidx, outp);
    }
}